// Round 3
// baseline (194.974 us; speedup 1.0000x reference)
//
#include <hip/hip_runtime.h>
#include <stdint.h>

#define N_NODES 50000
#define N_EDGES 800000
#define CAP 80        // bucket capacity; deg ~ Poisson(16), P(deg>80) ~ 1e-25
#define ZROW N_NODES  // zero-row index used to pad gather loops (rows 50000..50047 zeroed)
#define NBIN 81       // degree bins 0..80 for the balance sort
#define SCAT_BLOCKS 391   // 800000/8/256 rounded up -> 8 edges/thread
#define GEMM_BLOCKS 782   // 50048/64
// D_IN=128, H1=128, H2=64, C=2 — inputs fp32; intermediates bf16 (h1s UNscaled, h2s dinv-prescaled)

typedef __attribute__((ext_vector_type(8))) short short8;     // 8 bf16 (4 VGPRs)
typedef __attribute__((ext_vector_type(4))) float floatx4;    // MFMA acc

// ---------- bf16 helpers ----------
__device__ __forceinline__ float bflo(uint32_t u) { return __uint_as_float(u << 16); }
__device__ __forceinline__ float bfhi(uint32_t u) { return __uint_as_float(u & 0xffff0000u); }
__device__ __forceinline__ unsigned short f2b(float f) {
    uint32_t u = __float_as_uint(f);
    u += 0x7fffu + ((u >> 16) & 1u);   // RNE
    return (unsigned short)(u >> 16);
}

// ---------- 1. prep: zero counts (incl. pad) + bins, build Wt1/Wt2 bf16 transposes ----------
__global__ void k_prep(const float* __restrict__ W1, const float* __restrict__ W2,
                       unsigned short* __restrict__ Wt1, unsigned short* __restrict__ Wt2,
                       int* __restrict__ counts, int* __restrict__ bins) {
    int gid = blockIdx.x * 256 + threadIdx.x;
    if (gid < 16384) {                     // Wt1[n][k] = bf16(W1[k][n])
        int k = gid >> 7, n = gid & 127;
        Wt1[n * 128 + k] = f2b(W1[gid]);
    } else if (gid < 24576) {              // Wt2[n][k] = bf16(W2[k][n])
        int j = gid - 16384;
        int k = j >> 6, n = j & 63;
        Wt2[n * 128 + k] = f2b(W2[j]);
    } else if (gid < 74752) {              // zero counts[0..50175] (incl. ZROW pads)
        counts[gid - 24576] = 0;
    } else if (gid < 74944) {              // zero binCnt[96] + binOff[96]
        bins[gid - 74752] = 0;
    }
}

// ---------- 2. FUSED: scat (blocks 0..390) || gemm1 (blocks 391..1172) ----------
// R2 result: scat is transaction-bound (~53us regardless of occupancy); gemm1 rides
// under it for free (MfmaUtil 1%). Keep structure.
__global__ __launch_bounds__(256) void k_scat_gemm1(const int* __restrict__ src,
                                                    const int* __restrict__ dst,
                                                    int* __restrict__ counts,
                                                    int* __restrict__ csr,
                                                    const float* __restrict__ x,
                                                    const unsigned short* __restrict__ Wt1,
                                                    unsigned short* __restrict__ h1s,
                                                    unsigned short* __restrict__ h2s) {
    __shared__ unsigned short At[64 * 136];   // 17.0 KB (pad 8 bf16)
    __shared__ unsigned short Bt[128 * 136];  // 34.0 KB
    int t = threadIdx.x;
    if (blockIdx.x < SCAT_BLOCKS) {
        // ---- scat: one-pass CSR build, 8 edges/thread ----
        int i = blockIdx.x * 256 + t;         // edge-octet index
        if (i >= N_EDGES / 8) return;
        const int4* s4 = (const int4*)(src + i * 8);
        const int4* d4 = (const int4*)(dst + i * 8);
        int4 sa = s4[0], sb = s4[1];
        int4 da = d4[0], db = d4[1];
        int r0 = atomicAdd(&counts[da.x], 1);
        int r1 = atomicAdd(&counts[da.y], 1);
        int r2 = atomicAdd(&counts[da.z], 1);
        int r3 = atomicAdd(&counts[da.w], 1);
        int r4 = atomicAdd(&counts[db.x], 1);
        int r5 = atomicAdd(&counts[db.y], 1);
        int r6 = atomicAdd(&counts[db.z], 1);
        int r7 = atomicAdd(&counts[db.w], 1);
        if (r0 < CAP) csr[da.x * CAP + r0] = sa.x;
        if (r1 < CAP) csr[da.y * CAP + r1] = sa.y;
        if (r2 < CAP) csr[da.z * CAP + r2] = sa.z;
        if (r3 < CAP) csr[da.w * CAP + r3] = sa.w;
        if (r4 < CAP) csr[db.x * CAP + r4] = sb.x;
        if (r5 < CAP) csr[db.y * CAP + r5] = sb.y;
        if (r6 < CAP) csr[db.z * CAP + r6] = sb.z;
        if (r7 < CAP) csr[db.w * CAP + r7] = sb.w;
        return;
    }
    // ---- gemm1: h1s[v] = bf16(x[v]) @ bf16(W1), UNSCALED; 64 rows/block ----
    int row0 = (blockIdx.x - SCAT_BLOCKS) * 64;
    for (int i = t; i < 2048; i += 256) {     // stage Bt (Wt1 [n][k] bf16)
        int n = i >> 4, kc = (i & 15) * 8;
        *(uint4*)&Bt[n * 136 + kc] = *(const uint4*)(Wt1 + n * 128 + kc);
    }
    for (int i = t; i < 1024; i += 256) {     // stage At: fp32 -> bf16
        int r = i >> 4, kc = (i & 15) * 8;
        int g = row0 + r; if (g >= N_NODES) g = N_NODES - 1;
        const float* p = x + g * 128 + kc;
        float4 a = *(const float4*)p, b = *(const float4*)(p + 4);
        uint4 o;
        o.x = (uint32_t)f2b(a.x) | ((uint32_t)f2b(a.y) << 16);
        o.y = (uint32_t)f2b(a.z) | ((uint32_t)f2b(a.w) << 16);
        o.z = (uint32_t)f2b(b.x) | ((uint32_t)f2b(b.y) << 16);
        o.w = (uint32_t)f2b(b.z) | ((uint32_t)f2b(b.w) << 16);
        *(uint4*)&At[r * 136 + kc] = o;
    }
    __syncthreads();
    int wv = t >> 6, lane = t & 63;
    int m = lane & 15, qd = lane >> 4;
    floatx4 acc[8];
    #pragma unroll
    for (int c = 0; c < 8; c++) acc[c] = (floatx4){0.f, 0.f, 0.f, 0.f};
    const unsigned short* ap = &At[(wv * 16 + m) * 136 + qd * 8];
    const unsigned short* bp = &Bt[m * 136 + qd * 8];
    #pragma unroll
    for (int kk = 0; kk < 4; kk++) {
        short8 af = *(const short8*)(ap + kk * 32);
        #pragma unroll
        for (int c = 0; c < 8; c++) {
            short8 bf = *(const short8*)(bp + c * 16 * 136 + kk * 32);
            acc[c] = __builtin_amdgcn_mfma_f32_16x16x32_bf16(af, bf, acc[c], 0, 0, 0);
        }
    }
    #pragma unroll
    for (int reg = 0; reg < 4; reg++) {       // D[row=qd*4+reg][col=16c+m]
        int g = row0 + wv * 16 + qd * 4 + reg;
        if (g < N_NODES) {
            #pragma unroll
            for (int c = 0; c < 8; c++)
                h1s[g * 128 + c * 16 + m] = f2b(acc[c][reg]);
        } else {                              // zero pad rows (branchless-agg target)
            #pragma unroll
            for (int c = 0; c < 8; c++)
                h1s[g * 128 + c * 16 + m] = 0;
            #pragma unroll
            for (int c = 0; c < 4; c++)
                h2s[g * 64 + c * 16 + m] = 0;
        }
    }
}

// ---------- 3. degree-sort: bin counts -> scan -> rank+scatter (R3 load balance) ----------
// agg waves process 4 nodes and iterate max(deg of 4); Poisson(16) E[max4]~20.6 vs 16.
// Sorting nodes by degree makes wave-mates equal-degree: ~20% fewer gather iterations.
__global__ __launch_bounds__(256) void k_bin(const int* __restrict__ counts,
                                             int* __restrict__ binCnt) {
    __shared__ int lh[NBIN];
    int t = threadIdx.x;
    if (t < NBIN) lh[t] = 0;
    __syncthreads();
    int v = blockIdx.x * 256 + t;
    if (v < N_NODES) atomicAdd(&lh[min(counts[v], CAP)], 1);
    __syncthreads();
    if (t < NBIN && lh[t] > 0) atomicAdd(&binCnt[t], lh[t]);
}

__global__ void k_scan(const int* __restrict__ binCnt, int* __restrict__ binOff) {
    if (threadIdx.x == 0) {
        int r = 0;
        for (int i = 0; i < NBIN; i++) { binOff[i] = r; r += binCnt[i]; }
    }
}

__global__ __launch_bounds__(256) void k_perm(const int* __restrict__ counts,
                                              int* __restrict__ binOff,
                                              int* __restrict__ perm) {
    __shared__ int lh[NBIN];
    __shared__ int lbase[NBIN];
    int t = threadIdx.x;
    if (t < NBIN) lh[t] = 0;
    __syncthreads();
    int v = blockIdx.x * 256 + t;
    int d = 0, rank = 0;
    bool act = (v < N_NODES);
    if (act) {
        d = min(counts[v], CAP);
        rank = atomicAdd(&lh[d], 1);          // LDS rank within block
    }
    __syncthreads();
    if (t < NBIN && lh[t] > 0) lbase[t] = atomicAdd(&binOff[t], lh[t]);  // reserve range
    __syncthreads();
    if (act) perm[lbase[d] + rank] = v;
}

// ---------- 4. fused agg1 + GEMM2 (degree-sorted node order) ----------
// agg: r1[pv] = relu(dv * (Σ dinv[s]·h1s[s] + dv·h1s[pv]) + b1) -> LDS A-tile
// (16 equal-degree nodes/block via perm). Then 1 MFMA col-tile/wave.
__global__ __launch_bounds__(256) void k_agg1g2(const unsigned short* __restrict__ h1s,
                                                const unsigned short* __restrict__ Wt2,
                                                const int* __restrict__ csr,
                                                const int* __restrict__ counts,
                                                const int* __restrict__ perm,
                                                const float* __restrict__ b1,
                                                unsigned short* __restrict__ h2s) {
    __shared__ unsigned short Bt[64 * 136];   // Wt2 [n=64][k=128] staged
    __shared__ unsigned short At[16 * 136];   // r1 tile [16 rows][128 k]
    int t = threadIdx.x;
    for (int i = t; i < 1024; i += 256) {     // stage Bt2
        int n = i >> 4, kc = (i & 15) * 8;
        *(uint4*)&Bt[n * 136 + kc] = *(const uint4*)(Wt2 + n * 128 + kc);
    }
    int wv = t >> 6, lane = t & 63;
    int q = lane >> 4, l = lane & 15;
    int v0 = blockIdx.x * 16;
    int v = perm[v0 + wv * 4 + q];            // degree-sorted node
    int n = counts[v];
    float dv = rsqrtf((float)n + 1.0f);
    int n_eff = min(n, CAP);
    const int* cs = csr + v * CAP;
    int nmax = n_eff;
    nmax = max(nmax, __shfl_xor(nmax, 16));
    nmax = max(nmax, __shfl_xor(nmax, 32));
    float a0, a1, a2, a3, a4, a5, a6, a7;
    {   // self-loop row: dv * h1s[v] (h1s unscaled)
        uint4 p = *(const uint4*)(h1s + v * 128 + l * 8);
        a0 = dv * bflo(p.x); a1 = dv * bfhi(p.x); a2 = dv * bflo(p.y); a3 = dv * bfhi(p.y);
        a4 = dv * bflo(p.z); a5 = dv * bfhi(p.z); a6 = dv * bflo(p.w); a7 = dv * bfhi(p.w);
    }
    for (int base = 0; base < nmax; base += 16) {
        int idx = base + l;
        int e = (idx < n_eff) ? cs[idx] : ZROW;     // pad -> zero row
        float de = rsqrtf((float)counts[e] + 1.0f); // counts[ZROW..]=0 -> de=1, row=0
        int mm = nmax - base; if (mm > 16) mm = 16;
        #pragma unroll 4
        for (int i = 0; i < mm; i++) {
            int s = __shfl(e, (q << 4) + i);        // ZROW contributes exact 0.0f
            float di = __shfl(de, (q << 4) + i);
            uint4 p = *(const uint4*)(h1s + s * 128 + l * 8);
            a0 = fmaf(di, bflo(p.x), a0); a1 = fmaf(di, bfhi(p.x), a1);
            a2 = fmaf(di, bflo(p.y), a2); a3 = fmaf(di, bfhi(p.y), a3);
            a4 = fmaf(di, bflo(p.z), a4); a5 = fmaf(di, bfhi(p.z), a5);
            a6 = fmaf(di, bflo(p.w), a6); a7 = fmaf(di, bfhi(p.w), a7);
        }
    }
    {
        float4 bL = *(const float4*)(b1 + l * 8);
        float4 bH = *(const float4*)(b1 + l * 8 + 4);
        a0 = fmaxf(fmaf(dv, a0, bL.x), 0.f); a1 = fmaxf(fmaf(dv, a1, bL.y), 0.f);
        a2 = fmaxf(fmaf(dv, a2, bL.z), 0.f); a3 = fmaxf(fmaf(dv, a3, bL.w), 0.f);
        a4 = fmaxf(fmaf(dv, a4, bH.x), 0.f); a5 = fmaxf(fmaf(dv, a5, bH.y), 0.f);
        a6 = fmaxf(fmaf(dv, a6, bH.z), 0.f); a7 = fmaxf(fmaf(dv, a7, bH.w), 0.f);
        uint4 o;
        o.x = (uint32_t)f2b(a0) | ((uint32_t)f2b(a1) << 16);
        o.y = (uint32_t)f2b(a2) | ((uint32_t)f2b(a3) << 16);
        o.z = (uint32_t)f2b(a4) | ((uint32_t)f2b(a5) << 16);
        o.w = (uint32_t)f2b(a6) | ((uint32_t)f2b(a7) << 16);
        *(uint4*)&At[(wv * 4 + q) * 136 + l * 8] = o;   // r1 tile row
    }
    __syncthreads();
    // MFMA: wave wv -> col-tile wv (cols 16wv..16wv+15)
    int m = lane & 15, qd = lane >> 4;
    floatx4 acc = (floatx4){0.f, 0.f, 0.f, 0.f};
    const unsigned short* ap = &At[m * 136 + qd * 8];
    const unsigned short* bp = &Bt[(wv * 16 + m) * 136 + qd * 8];
    #pragma unroll
    for (int kk = 0; kk < 4; kk++) {
        short8 af = *(const short8*)(ap + kk * 32);
        short8 bf = *(const short8*)(bp + kk * 32);
        acc = __builtin_amdgcn_mfma_f32_16x16x32_bf16(af, bf, acc, 0, 0, 0);
    }
    #pragma unroll
    for (int reg = 0; reg < 4; reg++) {
        int pv = perm[v0 + qd * 4 + reg];             // tile row -> actual node
        float dg = rsqrtf((float)counts[pv] + 1.0f);  // prescale h2 rows
        h2s[pv * 64 + wv * 16 + m] = f2b(dg * acc[reg]);
    }
}

// ---------- 5. agg2 + head (degree-sorted, 2 neighbors/iter) ----------
// 16-lane group: lanes split lo8/hi8, each half reads a full 128B row (8x16B)
// of one neighbor of the pair; halves combined with shfl_xor(8) at the end.
__global__ __launch_bounds__(256) void k_agg2(const unsigned short* __restrict__ h2s,
                                              const int* __restrict__ csr,
                                              const int* __restrict__ counts,
                                              const int* __restrict__ perm,
                                              const float* __restrict__ b2,
                                              const float* __restrict__ Wo,
                                              const float* __restrict__ bo,
                                              float* __restrict__ out) {
    int wave = (blockIdx.x * 256 + threadIdx.x) >> 6;
    int lane = threadIdx.x & 63;
    int q = lane >> 4, l = lane & 15;
    int h = l >> 3, c = l & 7;                // half, column-octet
    int v = perm[wave * 4 + q];               // degree-sorted node
    int n = counts[v];
    float dv = rsqrtf((float)n + 1.0f);
    int n_eff = min(n, CAP);
    const int* cs = csr + v * CAP;
    int nmax = n_eff;
    nmax = max(nmax, __shfl_xor(nmax, 16));
    nmax = max(nmax, __shfl_xor(nmax, 32));
    float a0 = 0.f, a1 = 0.f, a2 = 0.f, a3 = 0.f, a4 = 0.f, a5 = 0.f, a6 = 0.f, a7 = 0.f;
    if (h == 0) {   // self-loop row (prescaled) into half 0 only
        uint4 p = *(const uint4*)(h2s + v * 64 + c * 8);
        a0 = bflo(p.x); a1 = bfhi(p.x); a2 = bflo(p.y); a3 = bfhi(p.y);
        a4 = bflo(p.z); a5 = bfhi(p.z); a6 = bflo(p.w); a7 = bfhi(p.w);
    }
    for (int base = 0; base < nmax; base += 16) {
        int idx = base + l;
        int e = (idx < n_eff) ? cs[idx] : ZROW;   // pad -> zero row (extra odd slot too)
        int mm = nmax - base; if (mm > 16) mm = 16;
        int pairs = (mm + 1) >> 1;
        #pragma unroll 4
        for (int i = 0; i < pairs; i++) {
            int s = __shfl(e, (q << 4) + 2 * i + h);   // half h takes pair element h
            uint4 p = *(const uint4*)(h2s + s * 64 + c * 8);
            a0 += bflo(p.x); a1 += bfhi(p.x); a2 += bflo(p.y); a3 += bfhi(p.y);
            a4 += bflo(p.z); a5 += bfhi(p.z); a6 += bflo(p.w); a7 += bfhi(p.w);
        }
    }
    // combine halves
    a0 += __shfl_xor(a0, 8); a1 += __shfl_xor(a1, 8);
    a2 += __shfl_xor(a2, 8); a3 += __shfl_xor(a3, 8);
    a4 += __shfl_xor(a4, 8); a5 += __shfl_xor(a5, 8);
    a6 += __shfl_xor(a6, 8); a7 += __shfl_xor(a7, 8);
    float4 bL = *(const float4*)(b2 + c * 8);
    float4 bH = *(const float4*)(b2 + c * 8 + 4);
    a0 = fmaxf(fmaf(dv, a0, bL.x), 0.f); a1 = fmaxf(fmaf(dv, a1, bL.y), 0.f);
    a2 = fmaxf(fmaf(dv, a2, bL.z), 0.f); a3 = fmaxf(fmaf(dv, a3, bL.w), 0.f);
    a4 = fmaxf(fmaf(dv, a4, bH.x), 0.f); a5 = fmaxf(fmaf(dv, a5, bH.y), 0.f);
    a6 = fmaxf(fmaf(dv, a6, bH.z), 0.f); a7 = fmaxf(fmaf(dv, a7, bH.w), 0.f);
    // head: logits over this lane's 8 cols (8c..8c+7), Wo row-major [64][2]
    float4 wA = *(const float4*)(Wo + c * 16);
    float4 wB = *(const float4*)(Wo + c * 16 + 4);
    float4 wC = *(const float4*)(Wo + c * 16 + 8);
    float4 wD = *(const float4*)(Wo + c * 16 + 12);
    float l0 = a0 * wA.x + a1 * wA.z + a2 * wB.x + a3 * wB.z
             + a4 * wC.x + a5 * wC.z + a6 * wD.x + a7 * wD.z;
    float l1 = a0 * wA.y + a1 * wA.w + a2 * wB.y + a3 * wB.w
             + a4 * wC.y + a5 * wC.w + a6 * wD.y + a7 * wD.w;
    l0 += __shfl_xor(l0, 1); l1 += __shfl_xor(l1, 1);
    l0 += __shfl_xor(l0, 2); l1 += __shfl_xor(l1, 2);
    l0 += __shfl_xor(l0, 4); l1 += __shfl_xor(l1, 4);
    if (l == 0) {
        float2 bof = *(const float2*)bo;
        l0 += bof.x; l1 += bof.y;
        float m = fmaxf(l0, l1);
        float ls = m + __logf(__expf(l0 - m) + __expf(l1 - m));
        *(float2*)(out + v * 2) = make_float2(l0 - ls, l1 - ls);
    }
}

extern "C" void kernel_launch(void* const* d_in, const int* in_sizes, int n_in,
                              void* d_out, int out_size, void* d_ws, size_t ws_size,
                              hipStream_t stream) {
    const float* x  = (const float*)d_in[0];
    const int* ei   = (const int*)d_in[1];
    const float* W1 = (const float*)d_in[2];
    const float* b1 = (const float*)d_in[3];
    const float* W2 = (const float*)d_in[4];
    const float* b2 = (const float*)d_in[5];
    const float* Wo = (const float*)d_in[6];
    const float* bo = (const float*)d_in[7];
    float* out      = (float*)d_out;
    const int* src = ei;             // edge_index[0]
    const int* dst = ei + N_EDGES;   // edge_index[1]

    char* w = (char*)d_ws;
    int* counts = (int*)(w + 0);                           // 200 KB (50176 ints, pads zeroed)
    int* csr    = (int*)(w + 200704);                      // 16 MB  [node][CAP]
    unsigned short* Wt1 = (unsigned short*)(w + 16200704); // 32 KB  [n=128][k=128]
    unsigned short* Wt2 = (unsigned short*)(w + 16233472); // 16 KB  [n=64][k=128]
    unsigned short* h1s = (unsigned short*)(w + 16249856); // 12.81 MB (50048 rows, pad zeroed)
    unsigned short* h2s = (unsigned short*)(w + 29062144); // 6.41 MB  (50048 rows, pad zeroed)
    int* perm   = (int*)(w + 35468288);                    // 200 KB degree-sorted node ids
    int* bins   = (int*)(w + 35668288);                    // binCnt[96] + binOff[96]
    int* binCnt = bins;
    int* binOff = bins + 96;
    // total ws usage: ~35.7 MB

    k_prep      <<<293, 256, 0, stream>>>(W1, W2, Wt1, Wt2, counts, bins);
    k_scat_gemm1<<<SCAT_BLOCKS + GEMM_BLOCKS, 256, 0, stream>>>(src, dst, counts, csr,
                                                                x, Wt1, h1s, h2s);
    k_bin       <<<196, 256, 0, stream>>>(counts, binCnt);
    k_scan      <<<1, 64, 0, stream>>>(binCnt, binOff);
    k_perm      <<<196, 256, 0, stream>>>(counts, binOff, perm);
    k_agg1g2    <<<3125, 256, 0, stream>>>(h1s, Wt2, csr, counts, perm, b1, h2s);
    k_agg2      <<<3125, 256, 0, stream>>>(h2s, csr, counts, perm, b2, Wo, bo, out);
}

// Round 4
// 183.867 us; speedup vs baseline: 1.0604x; 1.0604x over previous
//
#include <hip/hip_runtime.h>
#include <stdint.h>

#define N_NODES 50000
#define N_EDGES 800000
#define CAP 80        // bucket capacity; deg ~ Poisson(16), P(deg>80) ~ 1e-25
#define ZROW N_NODES  // zero-row index used to pad gather loops (rows 50000..50047 zeroed)
#define SCAT_BLOCKS 391   // 800000/8/256 rounded up -> 8 edges/thread
#define GEMM_BLOCKS 782   // 50048/64
// R4: counts padded to 1 counter / 64B line (stride 16 ints) — probe: is scat
// limited by per-line serialization of device-scope atomic RMWs? (16 counters/line
// x ~16 edges each = ~256 serialized RMWs/line before padding.)
#define CNT(v) ((v) << 4)
// D_IN=128, H1=128, H2=64, C=2 — inputs fp32; intermediates bf16 (h1s UNscaled, h2s dinv-prescaled)

typedef __attribute__((ext_vector_type(8))) short short8;     // 8 bf16 (4 VGPRs)
typedef __attribute__((ext_vector_type(4))) float floatx4;    // MFMA acc

// ---------- bf16 helpers ----------
__device__ __forceinline__ float bflo(uint32_t u) { return __uint_as_float(u << 16); }
__device__ __forceinline__ float bfhi(uint32_t u) { return __uint_as_float(u & 0xffff0000u); }
__device__ __forceinline__ unsigned short f2b(float f) {
    uint32_t u = __float_as_uint(f);
    u += 0x7fffu + ((u >> 16) & 1u);   // RNE
    return (unsigned short)(u >> 16);
}

// ---------- 1. prep: zero padded counts (incl. ZROW pads), build Wt1/Wt2 ----------
__global__ void k_prep(const float* __restrict__ W1, const float* __restrict__ W2,
                       unsigned short* __restrict__ Wt1, unsigned short* __restrict__ Wt2,
                       int* __restrict__ counts) {
    int gid = blockIdx.x * 256 + threadIdx.x;
    if (gid < 16384) {                     // Wt1[n][k] = bf16(W1[k][n])
        int k = gid >> 7, n = gid & 127;
        Wt1[n * 128 + k] = f2b(W1[gid]);
    } else if (gid < 24576) {              // Wt2[n][k] = bf16(W2[k][n])
        int j = gid - 16384;
        int k = j >> 6, n = j & 63;
        Wt2[n * 128 + k] = f2b(W2[j]);
    } else if (gid < 24576 + 802816) {     // zero counts[0..50175]*16 (3.2 MB)
        counts[gid - 24576] = 0;
    }
}

// ---------- 2. FUSED: scat (blocks 0..390) || gemm1 (blocks 391..1172) ----------
// R2 result: scat is transaction-bound (~51us regardless of occupancy); gemm1 rides
// under it for free (MfmaUtil 1%). R4: padded counters (see CNT).
__global__ __launch_bounds__(256) void k_scat_gemm1(const int* __restrict__ src,
                                                    const int* __restrict__ dst,
                                                    int* __restrict__ counts,
                                                    int* __restrict__ csr,
                                                    const float* __restrict__ x,
                                                    const unsigned short* __restrict__ Wt1,
                                                    unsigned short* __restrict__ h1s,
                                                    unsigned short* __restrict__ h2s) {
    __shared__ unsigned short At[64 * 136];   // 17.0 KB (pad 8 bf16)
    __shared__ unsigned short Bt[128 * 136];  // 34.0 KB
    int t = threadIdx.x;
    if (blockIdx.x < SCAT_BLOCKS) {
        // ---- scat: one-pass CSR build, 8 edges/thread ----
        int i = blockIdx.x * 256 + t;         // edge-octet index
        if (i >= N_EDGES / 8) return;
        const int4* s4 = (const int4*)(src + i * 8);
        const int4* d4 = (const int4*)(dst + i * 8);
        int4 sa = s4[0], sb = s4[1];
        int4 da = d4[0], db = d4[1];
        int r0 = atomicAdd(&counts[CNT(da.x)], 1);
        int r1 = atomicAdd(&counts[CNT(da.y)], 1);
        int r2 = atomicAdd(&counts[CNT(da.z)], 1);
        int r3 = atomicAdd(&counts[CNT(da.w)], 1);
        int r4 = atomicAdd(&counts[CNT(db.x)], 1);
        int r5 = atomicAdd(&counts[CNT(db.y)], 1);
        int r6 = atomicAdd(&counts[CNT(db.z)], 1);
        int r7 = atomicAdd(&counts[CNT(db.w)], 1);
        if (r0 < CAP) csr[da.x * CAP + r0] = sa.x;
        if (r1 < CAP) csr[da.y * CAP + r1] = sa.y;
        if (r2 < CAP) csr[da.z * CAP + r2] = sa.z;
        if (r3 < CAP) csr[da.w * CAP + r3] = sa.w;
        if (r4 < CAP) csr[db.x * CAP + r4] = sb.x;
        if (r5 < CAP) csr[db.y * CAP + r5] = sb.y;
        if (r6 < CAP) csr[db.z * CAP + r6] = sb.z;
        if (r7 < CAP) csr[db.w * CAP + r7] = sb.w;
        return;
    }
    // ---- gemm1: h1s[v] = bf16(x[v]) @ bf16(W1), UNSCALED; 64 rows/block ----
    int row0 = (blockIdx.x - SCAT_BLOCKS) * 64;
    for (int i = t; i < 2048; i += 256) {     // stage Bt (Wt1 [n][k] bf16)
        int n = i >> 4, kc = (i & 15) * 8;
        *(uint4*)&Bt[n * 136 + kc] = *(const uint4*)(Wt1 + n * 128 + kc);
    }
    for (int i = t; i < 1024; i += 256) {     // stage At: fp32 -> bf16
        int r = i >> 4, kc = (i & 15) * 8;
        int g = row0 + r; if (g >= N_NODES) g = N_NODES - 1;
        const float* p = x + g * 128 + kc;
        float4 a = *(const float4*)p, b = *(const float4*)(p + 4);
        uint4 o;
        o.x = (uint32_t)f2b(a.x) | ((uint32_t)f2b(a.y) << 16);
        o.y = (uint32_t)f2b(a.z) | ((uint32_t)f2b(a.w) << 16);
        o.z = (uint32_t)f2b(b.x) | ((uint32_t)f2b(b.y) << 16);
        o.w = (uint32_t)f2b(b.z) | ((uint32_t)f2b(b.w) << 16);
        *(uint4*)&At[r * 136 + kc] = o;
    }
    __syncthreads();
    int wv = t >> 6, lane = t & 63;
    int m = lane & 15, qd = lane >> 4;
    floatx4 acc[8];
    #pragma unroll
    for (int c = 0; c < 8; c++) acc[c] = (floatx4){0.f, 0.f, 0.f, 0.f};
    const unsigned short* ap = &At[(wv * 16 + m) * 136 + qd * 8];
    const unsigned short* bp = &Bt[m * 136 + qd * 8];
    #pragma unroll
    for (int kk = 0; kk < 4; kk++) {
        short8 af = *(const short8*)(ap + kk * 32);
        #pragma unroll
        for (int c = 0; c < 8; c++) {
            short8 bf = *(const short8*)(bp + c * 16 * 136 + kk * 32);
            acc[c] = __builtin_amdgcn_mfma_f32_16x16x32_bf16(af, bf, acc[c], 0, 0, 0);
        }
    }
    #pragma unroll
    for (int reg = 0; reg < 4; reg++) {       // D[row=qd*4+reg][col=16c+m]
        int g = row0 + wv * 16 + qd * 4 + reg;
        if (g < N_NODES) {
            #pragma unroll
            for (int c = 0; c < 8; c++)
                h1s[g * 128 + c * 16 + m] = f2b(acc[c][reg]);
        } else {                              // zero pad rows (branchless-agg target)
            #pragma unroll
            for (int c = 0; c < 8; c++)
                h1s[g * 128 + c * 16 + m] = 0;
            #pragma unroll
            for (int c = 0; c < 4; c++)
                h2s[g * 64 + c * 16 + m] = 0;
        }
    }
}

// ---------- 3. fused agg1 + GEMM2 ----------
// agg: r1[v] = relu(dv * (Σ dinv[s]·h1s[s] + dv·h1s[v]) + b1) -> LDS A-tile
// (16 nodes/block). h1s is UNSCALED; dinv[s] gathered from counts and broadcast
// with the neighbor index. Then 1 MFMA col-tile/wave.
__global__ __launch_bounds__(256) void k_agg1g2(const unsigned short* __restrict__ h1s,
                                                const unsigned short* __restrict__ Wt2,
                                                const int* __restrict__ csr,
                                                const int* __restrict__ counts,
                                                const float* __restrict__ b1,
                                                unsigned short* __restrict__ h2s) {
    __shared__ unsigned short Bt[64 * 136];   // Wt2 [n=64][k=128] staged
    __shared__ unsigned short At[16 * 136];   // r1 tile [16 rows][128 k]
    int t = threadIdx.x;
    for (int i = t; i < 1024; i += 256) {     // stage Bt2
        int n = i >> 4, kc = (i & 15) * 8;
        *(uint4*)&Bt[n * 136 + kc] = *(const uint4*)(Wt2 + n * 128 + kc);
    }
    int wv = t >> 6, lane = t & 63;
    int q = lane >> 4, l = lane & 15;
    int v0 = blockIdx.x * 16;
    int v = v0 + wv * 4 + q;                  // 50000 = 3125*16: always valid
    int n = counts[CNT(v)];
    float dv = rsqrtf((float)n + 1.0f);
    int n_eff = min(n, CAP);
    const int* cs = csr + v * CAP;
    int nmax = n_eff;
    nmax = max(nmax, __shfl_xor(nmax, 16));
    nmax = max(nmax, __shfl_xor(nmax, 32));
    float a0, a1, a2, a3, a4, a5, a6, a7;
    {   // self-loop row: dv * h1s[v] (h1s unscaled)
        uint4 p = *(const uint4*)(h1s + v * 128 + l * 8);
        a0 = dv * bflo(p.x); a1 = dv * bfhi(p.x); a2 = dv * bflo(p.y); a3 = dv * bfhi(p.y);
        a4 = dv * bflo(p.z); a5 = dv * bfhi(p.z); a6 = dv * bflo(p.w); a7 = dv * bfhi(p.w);
    }
    for (int base = 0; base < nmax; base += 16) {
        int idx = base + l;
        int e = (idx < n_eff) ? cs[idx] : ZROW;          // pad -> zero row
        float de = rsqrtf((float)counts[CNT(e)] + 1.0f); // counts[ZROW..]=0 -> de=1, row=0
        int mm = nmax - base; if (mm > 16) mm = 16;
        #pragma unroll 4
        for (int i = 0; i < mm; i++) {
            int s = __shfl(e, (q << 4) + i);        // ZROW contributes exact 0.0f
            float di = __shfl(de, (q << 4) + i);
            uint4 p = *(const uint4*)(h1s + s * 128 + l * 8);
            a0 = fmaf(di, bflo(p.x), a0); a1 = fmaf(di, bfhi(p.x), a1);
            a2 = fmaf(di, bflo(p.y), a2); a3 = fmaf(di, bfhi(p.y), a3);
            a4 = fmaf(di, bflo(p.z), a4); a5 = fmaf(di, bfhi(p.z), a5);
            a6 = fmaf(di, bflo(p.w), a6); a7 = fmaf(di, bfhi(p.w), a7);
        }
    }
    {
        float4 bL = *(const float4*)(b1 + l * 8);
        float4 bH = *(const float4*)(b1 + l * 8 + 4);
        a0 = fmaxf(fmaf(dv, a0, bL.x), 0.f); a1 = fmaxf(fmaf(dv, a1, bL.y), 0.f);
        a2 = fmaxf(fmaf(dv, a2, bL.z), 0.f); a3 = fmaxf(fmaf(dv, a3, bL.w), 0.f);
        a4 = fmaxf(fmaf(dv, a4, bH.x), 0.f); a5 = fmaxf(fmaf(dv, a5, bH.y), 0.f);
        a6 = fmaxf(fmaf(dv, a6, bH.z), 0.f); a7 = fmaxf(fmaf(dv, a7, bH.w), 0.f);
        uint4 o;
        o.x = (uint32_t)f2b(a0) | ((uint32_t)f2b(a1) << 16);
        o.y = (uint32_t)f2b(a2) | ((uint32_t)f2b(a3) << 16);
        o.z = (uint32_t)f2b(a4) | ((uint32_t)f2b(a5) << 16);
        o.w = (uint32_t)f2b(a6) | ((uint32_t)f2b(a7) << 16);
        *(uint4*)&At[(wv * 4 + q) * 136 + l * 8] = o;   // r1 tile row
    }
    __syncthreads();
    // MFMA: wave wv -> col-tile wv (cols 16wv..16wv+15)
    int m = lane & 15, qd = lane >> 4;
    floatx4 acc = (floatx4){0.f, 0.f, 0.f, 0.f};
    const unsigned short* ap = &At[m * 136 + qd * 8];
    const unsigned short* bp = &Bt[(wv * 16 + m) * 136 + qd * 8];
    #pragma unroll
    for (int kk = 0; kk < 4; kk++) {
        short8 af = *(const short8*)(ap + kk * 32);
        short8 bf = *(const short8*)(bp + kk * 32);
        acc = __builtin_amdgcn_mfma_f32_16x16x32_bf16(af, bf, acc, 0, 0, 0);
    }
    #pragma unroll
    for (int reg = 0; reg < 4; reg++) {
        int g = v0 + qd * 4 + reg;
        float dg = rsqrtf((float)counts[CNT(g)] + 1.0f);  // prescale h2 rows
        h2s[g * 64 + wv * 16 + m] = f2b(dg * acc[reg]);
    }
}

// ---------- 4. agg2 + head (2 neighbors/iter; verified in R3) ----------
// 16-lane group: lanes split lo8/hi8, each half reads a full 128B row (8x16B)
// of one neighbor of the pair; halves combined with shfl_xor(8) at the end.
__global__ __launch_bounds__(256) void k_agg2(const unsigned short* __restrict__ h2s,
                                              const int* __restrict__ csr,
                                              const int* __restrict__ counts,
                                              const float* __restrict__ b2,
                                              const float* __restrict__ Wo,
                                              const float* __restrict__ bo,
                                              float* __restrict__ out) {
    int wave = (blockIdx.x * 256 + threadIdx.x) >> 6;
    int lane = threadIdx.x & 63;
    int q = lane >> 4, l = lane & 15;
    int h = l >> 3, c = l & 7;                // half, column-octet
    int v = wave * 4 + q;                     // 3125*4*4 = 50000: always valid
    int n = counts[CNT(v)];
    float dv = rsqrtf((float)n + 1.0f);
    int n_eff = min(n, CAP);
    const int* cs = csr + v * CAP;
    int nmax = n_eff;
    nmax = max(nmax, __shfl_xor(nmax, 16));
    nmax = max(nmax, __shfl_xor(nmax, 32));
    float a0 = 0.f, a1 = 0.f, a2 = 0.f, a3 = 0.f, a4 = 0.f, a5 = 0.f, a6 = 0.f, a7 = 0.f;
    if (h == 0) {   // self-loop row (prescaled) into half 0 only
        uint4 p = *(const uint4*)(h2s + v * 64 + c * 8);
        a0 = bflo(p.x); a1 = bfhi(p.x); a2 = bflo(p.y); a3 = bfhi(p.y);
        a4 = bflo(p.z); a5 = bfhi(p.z); a6 = bflo(p.w); a7 = bfhi(p.w);
    }
    for (int base = 0; base < nmax; base += 16) {
        int idx = base + l;
        int e = (idx < n_eff) ? cs[idx] : ZROW;   // pad -> zero row (extra odd slot too)
        int mm = nmax - base; if (mm > 16) mm = 16;
        int pairs = (mm + 1) >> 1;
        #pragma unroll 4
        for (int i = 0; i < pairs; i++) {
            int s = __shfl(e, (q << 4) + 2 * i + h);   // half h takes pair element h
            uint4 p = *(const uint4*)(h2s + s * 64 + c * 8);
            a0 += bflo(p.x); a1 += bfhi(p.x); a2 += bflo(p.y); a3 += bfhi(p.y);
            a4 += bflo(p.z); a5 += bfhi(p.z); a6 += bflo(p.w); a7 += bfhi(p.w);
        }
    }
    // combine halves
    a0 += __shfl_xor(a0, 8); a1 += __shfl_xor(a1, 8);
    a2 += __shfl_xor(a2, 8); a3 += __shfl_xor(a3, 8);
    a4 += __shfl_xor(a4, 8); a5 += __shfl_xor(a5, 8);
    a6 += __shfl_xor(a6, 8); a7 += __shfl_xor(a7, 8);
    float4 bL = *(const float4*)(b2 + c * 8);
    float4 bH = *(const float4*)(b2 + c * 8 + 4);
    a0 = fmaxf(fmaf(dv, a0, bL.x), 0.f); a1 = fmaxf(fmaf(dv, a1, bL.y), 0.f);
    a2 = fmaxf(fmaf(dv, a2, bL.z), 0.f); a3 = fmaxf(fmaf(dv, a3, bL.w), 0.f);
    a4 = fmaxf(fmaf(dv, a4, bH.x), 0.f); a5 = fmaxf(fmaf(dv, a5, bH.y), 0.f);
    a6 = fmaxf(fmaf(dv, a6, bH.z), 0.f); a7 = fmaxf(fmaf(dv, a7, bH.w), 0.f);
    // head: logits over this lane's 8 cols (8c..8c+7), Wo row-major [64][2]
    float4 wA = *(const float4*)(Wo + c * 16);
    float4 wB = *(const float4*)(Wo + c * 16 + 4);
    float4 wC = *(const float4*)(Wo + c * 16 + 8);
    float4 wD = *(const float4*)(Wo + c * 16 + 12);
    float l0 = a0 * wA.x + a1 * wA.z + a2 * wB.x + a3 * wB.z
             + a4 * wC.x + a5 * wC.z + a6 * wD.x + a7 * wD.z;
    float l1 = a0 * wA.y + a1 * wA.w + a2 * wB.y + a3 * wB.w
             + a4 * wC.y + a5 * wC.w + a6 * wD.y + a7 * wD.w;
    l0 += __shfl_xor(l0, 1); l1 += __shfl_xor(l1, 1);
    l0 += __shfl_xor(l0, 2); l1 += __shfl_xor(l1, 2);
    l0 += __shfl_xor(l0, 4); l1 += __shfl_xor(l1, 4);
    if (l == 0) {
        float2 bof = *(const float2*)bo;
        l0 += bof.x; l1 += bof.y;
        float m = fmaxf(l0, l1);
        float ls = m + __logf(__expf(l0 - m) + __expf(l1 - m));
        *(float2*)(out + v * 2) = make_float2(l0 - ls, l1 - ls);
    }
}

extern "C" void kernel_launch(void* const* d_in, const int* in_sizes, int n_in,
                              void* d_out, int out_size, void* d_ws, size_t ws_size,
                              hipStream_t stream) {
    const float* x  = (const float*)d_in[0];
    const int* ei   = (const int*)d_in[1];
    const float* W1 = (const float*)d_in[2];
    const float* b1 = (const float*)d_in[3];
    const float* W2 = (const float*)d_in[4];
    const float* b2 = (const float*)d_in[5];
    const float* Wo = (const float*)d_in[6];
    const float* bo = (const float*)d_in[7];
    float* out      = (float*)d_out;
    const int* src = ei;             // edge_index[0]
    const int* dst = ei + N_EDGES;   // edge_index[1]

    char* w = (char*)d_ws;
    int* counts = (int*)(w + 0);                           // 3.21 MB (50176 x stride-16, pads zeroed)
    int* csr    = (int*)(w + 3211264);                     // 16 MB  [node][CAP]
    unsigned short* Wt1 = (unsigned short*)(w + 19211264); // 32 KB  [n=128][k=128]
    unsigned short* Wt2 = (unsigned short*)(w + 19244032); // 16 KB  [n=64][k=128]
    unsigned short* h1s = (unsigned short*)(w + 19260416); // 12.81 MB (50048 rows, pad zeroed)
    unsigned short* h2s = (unsigned short*)(w + 32072704); // 6.41 MB  (50048 rows, pad zeroed)
    // total ws usage: ~38.5 MB

    k_prep      <<<3232, 256, 0, stream>>>(W1, W2, Wt1, Wt2, counts);
    k_scat_gemm1<<<SCAT_BLOCKS + GEMM_BLOCKS, 256, 0, stream>>>(src, dst, counts, csr,
                                                                x, Wt1, h1s, h2s);
    k_agg1g2    <<<3125, 256, 0, stream>>>(h1s, Wt2, csr, counts, b1, h2s);
    k_agg2      <<<3125, 256, 0, stream>>>(h2s, csr, counts, b2, Wo, bo, out);
}